// Round 6
// baseline (143.448 us; speedup 1.0000x reference)
//
#include <hip/hip_runtime.h>

// Conv2d 3x3 s1 p1, N=16 C=64 H=W=112 F=64, fp32 in/out, bf16 MFMA implicit GEMM.
// R6: three-kernel plan.
//  1) conv_wprep : weights OIHW fp32 -> bf16 B-fragment tensor [t][cb][koct][f][j]
//  2) conv_xform : x NCHW fp32 -> PADDED NHWC bf16 xt[16][114][114][64] (zero borders)
//  3) conv_mfma  : LDS-FREE, barrier-free implicit GEMM. 1792 single-wave blocks
//     (exactly 7 waves/CU, all co-resident). Wave = one (n,h) output row, all 64 f.
//     A-frag = one coalesced dwordx4 from L2-hot xt; B-frags from L2-hot wbf;
//     D stored directly to NCHW (per-f 64B segments, adjacent mt merge in L2).

typedef __attribute__((ext_vector_type(8))) short bf16x8;
typedef __attribute__((ext_vector_type(4))) float f32x4;

#define CIN 64
#define COUT 64
#define HH 112
#define WW 112
#define XTW 114                    // padded spatial dim
#define WBF_BYTES 73728            // 36864 shorts

__device__ __forceinline__ unsigned short f2bf(float f) {
    unsigned u = __builtin_bit_cast(unsigned, f);
    u += 0x7FFFu + ((u >> 16) & 1u);   // round-to-nearest-even
    return (unsigned short)(u >> 16);
}

#if __has_builtin(__builtin_amdgcn_cvt_pk_bf16_f32)
__device__ __forceinline__ unsigned pk2bf(float a, float b) {
    typedef __attribute__((ext_vector_type(2))) __bf16 bf16x2;
    bf16x2 r = __builtin_amdgcn_cvt_pk_bf16_f32(a, b);
    return __builtin_bit_cast(unsigned, r);
}
#else
__device__ __forceinline__ unsigned pk2bf(float a, float b) {
    return (unsigned)f2bf(a) | ((unsigned)f2bf(b) << 16);
}
#endif

// ---- one-time weight conversion: OIHW fp32 -> bf16 [t][cb][koct][f][j] ----
__global__ void conv_wprep(const float* __restrict__ w, short* __restrict__ wbf) {
    int i = blockIdx.x * 256 + threadIdx.x;    // grid sized to exactly 36864
    int j = i & 7;
    int f = (i >> 3) & 63;
    int koct = (i >> 9) & 3;
    int cb = (i >> 11) & 1;
    int t = i >> 12;
    int c = cb * 32 + koct * 8 + j;
    int ky = t / 3, kx = t - ky * 3;
    wbf[i] = (short)f2bf(w[((f * CIN + c) * 3 + ky) * 3 + kx]);
}

// ---- layout transform: NCHW fp32 -> padded NHWC bf16 (zero borders) ----
// block = one (n, padded-row hp). Interior rows transpose through a small LDS
// tile [112 w][66 shorts-pitch]; border rows/cols written as zeros.
__global__ __launch_bounds__(256)
void conv_xform(const float* __restrict__ x, short* __restrict__ xt) {
    const int n = blockIdx.x;
    const int hp = blockIdx.y;                 // 0..113
    const int tid = threadIdx.x;
    short* dst = xt + ((size_t)(n * XTW + hp) * XTW) * 64;

    if (hp == 0 || hp == XTW - 1) {            // top/bottom border rows: all zero
        for (int i = tid; i < XTW * 16; i += 256)      // 1824 dwordx2 units
            *(uint2*)(dst + i * 4) = (uint2){0u, 0u};
        return;
    }

    __shared__ short lrow[WW * 66];            // pitch 66 shorts (33 dwords)
    const int h = hp - 1;
    // stage: 16 c-quads x 28 w4-units; coalesced float4 reads, packed bf16
    for (int u = tid; u < 448; u += 256) {
        int w4 = u % 28;
        int cq = u / 28;
        int c = cq * 4;
        const float* px = x + (((size_t)(n * CIN + c) * HH + h) * WW) + w4 * 4;
        const float4 v0 = *(const float4*)px;
        const float4 v1 = *(const float4*)(px + HH * WW);
        const float4 v2 = *(const float4*)(px + 2 * HH * WW);
        const float4 v3 = *(const float4*)(px + 3 * HH * WW);
        float a0[4] = {v0.x, v0.y, v0.z, v0.w};
        float a1[4] = {v1.x, v1.y, v1.z, v1.w};
        float a2[4] = {v2.x, v2.y, v2.z, v2.w};
        float a3[4] = {v3.x, v3.y, v3.z, v3.w};
#pragma unroll
        for (int dw = 0; dw < 4; ++dw) {
            int w = w4 * 4 + dw;
            *(unsigned*)&lrow[w * 66 + c]     = pk2bf(a0[dw], a1[dw]);
            *(unsigned*)&lrow[w * 66 + c + 2] = pk2bf(a2[dw], a3[dw]);
        }
    }
    __syncthreads();
    // write out NHWC coalesced: 1792 data units + 32 side-border units (dwordx2)
    for (int u = tid; u < 1824; u += 256) {
        uint2 val;
        int wp, s;
        if (u < 1792) {
            int p = u >> 4;
            s = u & 15;
            val.x = *(const unsigned*)&lrow[p * 66 + s * 4];
            val.y = *(const unsigned*)&lrow[p * 66 + s * 4 + 2];
            wp = p + 1;
        } else {
            int b = u - 1792;
            wp = (b >> 4) ? (XTW - 1) : 0;
            s = b & 15;
            val = (uint2){0u, 0u};
        }
        *(uint2*)(dst + wp * 64 + s * 4) = val;
    }
}

// ---- the conv: LDS-free, barrier-free, 1 wave per (n, h) row ----
__global__ __launch_bounds__(64, 2)
void conv_mfma(const short* __restrict__ xt, const short* __restrict__ wbf,
               const float* __restrict__ bias, float* __restrict__ out)
{
    const int n = blockIdx.x;
    const int h = blockIdx.y;
    const int lane = threadIdx.x;
    const int lm = lane & 15;          // A: pixel ; B/D: f
    const int q  = lane >> 4;          // k-octet

    float bsr[4];
#pragma unroll
    for (int ntl = 0; ntl < 4; ++ntl) bsr[ntl] = bias[ntl * 16 + lm];

    // A base: lane (lm,q) reads xt[n][h+ky][mt*16+lm+kx][cb*32 + q*8 ..+7]
    const short* arow = xt + ((size_t)(n * XTW + h) * XTW + lm) * 64 + q * 8;
    // B base: wbf[(t*8 + cb*4 + q)*512 + (ntl*16+lm)*8]
    const short* wl = wbf + q * 512 + lm * 8;

    f32x4 acc[7][4];
#pragma unroll
    for (int mt = 0; mt < 7; ++mt)
#pragma unroll
        for (int ntl = 0; ntl < 4; ++ntl) acc[mt][ntl] = (f32x4){0.f, 0.f, 0.f, 0.f};

#pragma unroll 1   // keep VGPRs bounded; scalar tap math is SALU-cheap
    for (int ht = 0; ht < 18; ++ht) {
        const int t = ht >> 1, cb = ht & 1;
        const int ky = t / 3, kx = t - ky * 3;

        // batch-issue the 7 A-frags for this half-tap (independent loads)
        const short* ab = arow + (ky * XTW + kx) * 64 + cb * 32;
        bf16x8 a[7];
#pragma unroll
        for (int mt = 0; mt < 7; ++mt)
            a[mt] = *(const bf16x8*)(ab + mt * 1024);      // mt*16 pixels * 64ch

        // B fragments for this half-tap (4 n-tiles)
        const short* wn = wl + (t * 8 + cb * 4) * 512;
        bf16x8 Bf[4];
#pragma unroll
        for (int ntl = 0; ntl < 4; ++ntl)
            Bf[ntl] = *(const bf16x8*)(wn + ntl * 128);

#pragma unroll
        for (int mt = 0; mt < 7; ++mt)
#pragma unroll
            for (int ntl = 0; ntl < 4; ++ntl)
                acc[mt][ntl] = __builtin_amdgcn_mfma_f32_16x16x32_bf16(
                    a[mt], Bf[ntl], acc[mt][ntl], 0, 0, 0);
    }

    // ---- direct stores: lane (lm,q) holds f=ntl*16+lm, w=mt*16+q*4..+3 ----
#pragma unroll
    for (int ntl = 0; ntl < 4; ++ntl) {
        float* ob = out + (((size_t)(n * COUT + ntl * 16 + lm) * HH + h) * WW) + q * 4;
        const float b = bsr[ntl];
#pragma unroll
        for (int mt = 0; mt < 7; ++mt) {
            const f32x4 v = acc[mt][ntl];
            float4 s;
            s.x = v[0] + b; s.y = v[1] + b; s.z = v[2] + b; s.w = v[3] + b;
            *(float4*)(ob + mt * 16) = s;
        }
    }
}

extern "C" void kernel_launch(void* const* d_in, const int* in_sizes, int n_in,
                              void* d_out, int out_size, void* d_ws, size_t ws_size,
                              hipStream_t stream) {
    const float* x = (const float*)d_in[0];
    const float* w = (const float*)d_in[1];
    const float* b = (const float*)d_in[2];
    float* out = (float*)d_out;
    short* wbf = (short*)d_ws;                          // 73728 B
    short* xt  = (short*)((char*)d_ws + WBF_BYTES);     // 16*114*114*64*2 = 26.6 MB

    conv_wprep<<<144, 256, 0, stream>>>(w, wbf);        // 144*256 == 36864 exactly
    conv_xform<<<dim3(16, XTW), 256, 0, stream>>>(x, xt);
    conv_mfma<<<dim3(16, HH), 64, 0, stream>>>(xt, wbf, b, out);
}

// Round 7
// 141.294 us; speedup vs baseline: 1.0152x; 1.0152x over previous
//
#include <hip/hip_runtime.h>

// Conv2d 3x3 s1 p1, N=16 C=64 H=W=112 F=64, fp32 in/out, bf16 MFMA implicit GEMM.
// R7: same three-kernel plan as R6, but conv_mfma is software-pipelined:
//  - 18 half-taps fully unrolled with ping-pong A/B register buffers
//    (loads for ht+1 in flight under ht's 28 MFMAs)
//  - __launch_bounds__(64,2) keeps VGPR+AGPR <= 256 so 2 waves/SIMD co-reside
//    (paired-wave MFMA issue covers the remaining L2 latency)

typedef __attribute__((ext_vector_type(8))) short bf16x8;
typedef __attribute__((ext_vector_type(4))) float f32x4;

#define CIN 64
#define COUT 64
#define HH 112
#define WW 112
#define XTW 114                    // padded spatial dim
#define WBF_BYTES 73728            // 36864 shorts

__device__ __forceinline__ unsigned short f2bf(float f) {
    unsigned u = __builtin_bit_cast(unsigned, f);
    u += 0x7FFFu + ((u >> 16) & 1u);   // round-to-nearest-even
    return (unsigned short)(u >> 16);
}

#if __has_builtin(__builtin_amdgcn_cvt_pk_bf16_f32)
__device__ __forceinline__ unsigned pk2bf(float a, float b) {
    typedef __attribute__((ext_vector_type(2))) __bf16 bf16x2;
    bf16x2 r = __builtin_amdgcn_cvt_pk_bf16_f32(a, b);
    return __builtin_bit_cast(unsigned, r);
}
#else
__device__ __forceinline__ unsigned pk2bf(float a, float b) {
    return (unsigned)f2bf(a) | ((unsigned)f2bf(b) << 16);
}
#endif

// ---- one-time weight conversion: OIHW fp32 -> bf16 [t][cb][koct][f][j] ----
__global__ void conv_wprep(const float* __restrict__ w, short* __restrict__ wbf) {
    int i = blockIdx.x * 256 + threadIdx.x;    // grid sized to exactly 36864
    int j = i & 7;
    int f = (i >> 3) & 63;
    int koct = (i >> 9) & 3;
    int cb = (i >> 11) & 1;
    int t = i >> 12;
    int c = cb * 32 + koct * 8 + j;
    int ky = t / 3, kx = t - ky * 3;
    wbf[i] = (short)f2bf(w[((f * CIN + c) * 3 + ky) * 3 + kx]);
}

// ---- layout transform: NCHW fp32 -> padded NHWC bf16 (zero borders) ----
__global__ __launch_bounds__(256)
void conv_xform(const float* __restrict__ x, short* __restrict__ xt) {
    const int n = blockIdx.x;
    const int hp = blockIdx.y;                 // 0..113
    const int tid = threadIdx.x;
    short* dst = xt + ((size_t)(n * XTW + hp) * XTW) * 64;

    if (hp == 0 || hp == XTW - 1) {            // top/bottom border rows: all zero
        for (int i = tid; i < XTW * 16; i += 256)      // 1824 dwordx2 units
            *(uint2*)(dst + i * 4) = (uint2){0u, 0u};
        return;
    }

    __shared__ short lrow[WW * 66];            // pitch 66 shorts (33 dwords)
    const int h = hp - 1;
    // stage: 16 c-quads x 28 w4-units; coalesced float4 reads, packed bf16
    for (int u = tid; u < 448; u += 256) {
        int w4 = u % 28;
        int cq = u / 28;
        int c = cq * 4;
        const float* px = x + (((size_t)(n * CIN + c) * HH + h) * WW) + w4 * 4;
        const float4 v0 = *(const float4*)px;
        const float4 v1 = *(const float4*)(px + HH * WW);
        const float4 v2 = *(const float4*)(px + 2 * HH * WW);
        const float4 v3 = *(const float4*)(px + 3 * HH * WW);
        float a0[4] = {v0.x, v0.y, v0.z, v0.w};
        float a1[4] = {v1.x, v1.y, v1.z, v1.w};
        float a2[4] = {v2.x, v2.y, v2.z, v2.w};
        float a3[4] = {v3.x, v3.y, v3.z, v3.w};
#pragma unroll
        for (int dw = 0; dw < 4; ++dw) {
            int w = w4 * 4 + dw;
            *(unsigned*)&lrow[w * 66 + c]     = pk2bf(a0[dw], a1[dw]);
            *(unsigned*)&lrow[w * 66 + c + 2] = pk2bf(a2[dw], a3[dw]);
        }
    }
    __syncthreads();
    // write out NHWC coalesced: 1792 data units + 32 side-border units (dwordx2)
    for (int u = tid; u < 1824; u += 256) {
        uint2 val;
        int wp, s;
        if (u < 1792) {
            int p = u >> 4;
            s = u & 15;
            val.x = *(const unsigned*)&lrow[p * 66 + s * 4];
            val.y = *(const unsigned*)&lrow[p * 66 + s * 4 + 2];
            wp = p + 1;
        } else {
            int b = u - 1792;
            wp = (b >> 4) ? (XTW - 1) : 0;
            s = b & 15;
            val = (uint2){0u, 0u};
        }
        *(uint2*)(dst + wp * 64 + s * 4) = val;
    }
}

// ---- the conv: LDS-free, barrier-free, software-pipelined half-taps ----
__global__ __launch_bounds__(64, 2)
void conv_mfma(const short* __restrict__ xt, const short* __restrict__ wbf,
               const float* __restrict__ bias, float* __restrict__ out)
{
    const int n = blockIdx.x;
    const int h = blockIdx.y;
    const int lane = threadIdx.x;
    const int lm = lane & 15;          // A: pixel ; B/D: f
    const int q  = lane >> 4;          // k-octet

    float bsr[4];
#pragma unroll
    for (int ntl = 0; ntl < 4; ++ntl) bsr[ntl] = bias[ntl * 16 + lm];

    // A base: lane (lm,q) reads xt[n][h+ky][mt*16+lm+kx][cb*32 + q*8 ..+7]
    const short* arow = xt + ((size_t)(n * XTW + h) * XTW + lm) * 64 + q * 8;
    // B base: wbf[(t*8 + cb*4 + q)*512 + (ntl*16+lm)*8]
    const short* wl = wbf + q * 512 + lm * 8;

    f32x4 acc[7][4];
#pragma unroll
    for (int mt = 0; mt < 7; ++mt)
#pragma unroll
        for (int ntl = 0; ntl < 4; ++ntl) acc[mt][ntl] = (f32x4){0.f, 0.f, 0.f, 0.f};

    // ping-pong register buffers; ht = t*2 + cb, fully unrolled so indices fold
    bf16x8 a[2][7];
    bf16x8 Bf[2][4];

    // prefetch half-tap 0 (t=0: ky=0,kx=0, cb=0)
#pragma unroll
    for (int mt = 0; mt < 7; ++mt)
        a[0][mt] = *(const bf16x8*)(arow + mt * 1024);
#pragma unroll
    for (int ntl = 0; ntl < 4; ++ntl)
        Bf[0][ntl] = *(const bf16x8*)(wl + ntl * 128);

#pragma unroll
    for (int ht = 0; ht < 18; ++ht) {
        const int cur = ht & 1;
        const int nxt = cur ^ 1;
        if (ht < 17) {
            const int hn = ht + 1;
            const int tn = hn >> 1, cbn = hn & 1;
            const int kyn = tn / 3, kxn = tn - kyn * 3;
            const short* ab = arow + (kyn * XTW + kxn) * 64 + cbn * 32;
#pragma unroll
            for (int mt = 0; mt < 7; ++mt)
                a[nxt][mt] = *(const bf16x8*)(ab + mt * 1024);
            const short* wn = wl + (tn * 8 + cbn * 4) * 512;
#pragma unroll
            for (int ntl = 0; ntl < 4; ++ntl)
                Bf[nxt][ntl] = *(const bf16x8*)(wn + ntl * 128);
        }
#pragma unroll
        for (int mt = 0; mt < 7; ++mt)
#pragma unroll
            for (int ntl = 0; ntl < 4; ++ntl)
                acc[mt][ntl] = __builtin_amdgcn_mfma_f32_16x16x32_bf16(
                    a[cur][mt], Bf[cur][ntl], acc[mt][ntl], 0, 0, 0);
    }

    // ---- direct stores: lane (lm,q) holds f=ntl*16+lm, w=mt*16+q*4..+3 ----
#pragma unroll
    for (int ntl = 0; ntl < 4; ++ntl) {
        float* ob = out + (((size_t)(n * COUT + ntl * 16 + lm) * HH + h) * WW) + q * 4;
        const float b = bsr[ntl];
#pragma unroll
        for (int mt = 0; mt < 7; ++mt) {
            const f32x4 v = acc[mt][ntl];
            float4 s;
            s.x = v[0] + b; s.y = v[1] + b; s.z = v[2] + b; s.w = v[3] + b;
            *(float4*)(ob + mt * 16) = s;
        }
    }
}

extern "C" void kernel_launch(void* const* d_in, const int* in_sizes, int n_in,
                              void* d_out, int out_size, void* d_ws, size_t ws_size,
                              hipStream_t stream) {
    const float* x = (const float*)d_in[0];
    const float* w = (const float*)d_in[1];
    const float* b = (const float*)d_in[2];
    float* out = (float*)d_out;
    short* wbf = (short*)d_ws;                          // 73728 B
    short* xt  = (short*)((char*)d_ws + WBF_BYTES);     // 16*114*114*64*2 = 26.6 MB

    conv_wprep<<<144, 256, 0, stream>>>(w, wbf);        // 144*256 == 36864 exactly
    conv_xform<<<dim3(16, XTW), 256, 0, stream>>>(x, xt);
    conv_mfma<<<dim3(16, HH), 64, 0, stream>>>(xt, wbf, b, out);
}